// Round 7
// baseline (123.392 us; speedup 1.0000x reference)
//
#include <hip/hip_runtime.h>
#include <hip/hip_bf16.h>

#define NODE 1024
#define BS 8

struct alignas(8) bf4 { __hip_bfloat16 a, b, c, d; };
typedef short short8 __attribute__((ext_vector_type(8)));
typedef float f32x16 __attribute__((ext_vector_type(16)));

__device__ __forceinline__ short bf16bits(float f) {
    __hip_bfloat16 h = __float2bfloat16(f);
    return *reinterpret_cast<short*>(&h);
}
__device__ __forceinline__ float bitstofl(short s) {
    unsigned u = ((unsigned)(unsigned short)s) << 16;
    return __uint_as_float(u);
}

// ===========================================================================
// FRAGMENT LAYOUTS (mfma_f32_32x32x16_bf16: lane = l31 + 32*hi holds
// elem (row=l31, k = kstep*16 + hi*8 + j), j=0..7 -> 16B per lane)
//   A16f(b,n,m):  (((b*32+(n>>5))*64 + (m>>4))*2 + ((m>>3)&1))*256 + (n&31)*8 + (m&7)
//   xTf (b,f,m):  (((b*2+(f>>5))*64 + (m>>4))*2 + ((m>>3)&1))*256 + (f&31)*8 + (m&7)
//   xgf (row,k):  ((row>>5)*13 + (k>>4))*512 + ((k>>3)&1)*256 + (row&31)*8 + (k&7)
//   wtf (d,o,k):  (((d*2+(o>>5))*13 + (k>>4))*2 + ((k>>3)&1))*256 + (o&31)*8 + (k&7)
// ===========================================================================

// ---------------------------------------------------------------------------
// K1: block = (b, 32-row tile). 8 waves, wave w owns m in [w*128, w*128+128),
// lane (l31=row, hi) owns 64 m's. Wave-local + LDS sum reduce. Writes A16f
// fragments: 16B chunks, fully coalesced. No max-subtract (logits << 88).
// ---------------------------------------------------------------------------
__global__ __launch_bounds__(512) void k_attn(const float* __restrict__ ne,
                                              const float* __restrict__ t,
                                              const float* __restrict__ nt,
                                              __hip_bfloat16* __restrict__ A16f) {
    __shared__ float nel[NODE * 11];
    __shared__ float ssum[8][32];
    int tid = threadIdx.x;
    int w = tid >> 6, lane = tid & 63;
    int l31 = lane & 31, hi = lane >> 5;
    int bidx = blockIdx.x;            // b*32 + ntile
    int b = bidx >> 5;
    int n = (bidx & 31) * 32 + l31;

    for (int i = tid; i < NODE * 10; i += 512) nel[(i / 10) * 11 + (i % 10)] = ne[i];

    float at = 0.f;
#pragma unroll
    for (int j = 0; j < 6; ++j) at += nt[b * 6 + j] * t[b * 6 + j];
    __syncthreads();

    float nr[10];
#pragma unroll
    for (int d = 0; d < 10; ++d) nr[d] = nel[n * 11 + d];

    int mbase = w * 128 + hi * 64;
    float z[64];
#pragma unroll
    for (int m = 0; m < 64; ++m) {
        const float* row = &nel[(mbase + m) * 11];
        float s = 0.f;
#pragma unroll
        for (int d = 0; d < 10; ++d) s += nr[d] * row[d];
        z[m] = s;
    }

    short8 u16[8];
    float s = 0.f;
#pragma unroll
    for (int c = 0; c < 8; ++c) {
        short8 pk;
#pragma unroll
        for (int j = 0; j < 8; ++j) {
            float u = __expf(fmaxf(z[c * 8 + j] + at, 0.f));
            s += u;
            pk[j] = bf16bits(u);
        }
        u16[c] = pk;
    }
    s += __shfl_xor(s, 32);
    if (hi == 0) ssum[w][l31] = s;
    __syncthreads();
    float tot = 0.f;
#pragma unroll
    for (int ww = 0; ww < 8; ++ww) tot += ssum[ww][l31];
    float inv = 1.f / tot;

    __hip_bfloat16* base = A16f + ((size_t)(bidx * 64 + w * 8 + hi * 4) * 2) * 256 + l31 * 8;
#pragma unroll
    for (int c = 0; c < 8; ++c) {
        short8 pk = u16[c];
        short8 o;
#pragma unroll
        for (int j = 0; j < 8; ++j) o[j] = bf16bits(bitstofl(pk[j]) * inv);
        *(short8*)(base + c * 256) = o;
    }
}

// ---------------------------------------------------------------------------
// K2 (merged): blocks 0..127 : x -> xgf ksteps 0..3 + bias kstep 12 + xTf
//              blocks 128..143: W,bp -> wtf fragments
// ---------------------------------------------------------------------------
__global__ __launch_bounds__(256) void k_prepw(const float* __restrict__ x,
                                               const float* __restrict__ W,
                                               const float* __restrict__ bp,
                                               __hip_bfloat16* __restrict__ xTf,
                                               __hip_bfloat16* __restrict__ xgf,
                                               __hip_bfloat16* __restrict__ wtf) {
    int tid = threadIdx.x;
    if (blockIdx.x < 128) {
        __shared__ __hip_bfloat16 T[64][72];      // [f][node-local]
        int b = blockIdx.x >> 4;
        int n0 = (blockIdx.x & 15) * 64;
        // phase 1: read x (8 floats/thread x2), write xgf k 0..63, stash T
#pragma unroll
        for (int it = 0; it < 2; ++it) {
            int i = it * 256 + tid;
            int l31 = i & 31, hi2 = (i >> 5) & 1, ks = (i >> 6) & 3, rt = i >> 8;
            int node = n0 + rt * 32 + l31;
            const float* src = x + ((size_t)b * 1024 + node) * 64 + ks * 16 + hi2 * 8;
            short8 o;
#pragma unroll
            for (int j = 0; j < 8; ++j) o[j] = bf16bits(src[j]);
            size_t rtg = (size_t)b * 32 + (n0 >> 5) + rt;
            *(short8*)(xgf + (rtg * 13 + ks) * 512 + hi2 * 256 + l31 * 8) = o;
#pragma unroll
            for (int j = 0; j < 8; ++j) {
                __hip_bfloat16 h;
                *reinterpret_cast<short*>(&h) = o[j];
                T[ks * 16 + hi2 * 8 + j][rt * 32 + l31] = h;
            }
        }
        // bias window: kstep 12 (k=192 -> 1.0, else 0)
        for (int i = tid; i < 1024; i += 256) {
            int rt = i >> 9, e = i & 511;
            size_t rtg = (size_t)b * 32 + (n0 >> 5) + rt;
            float val = ((e & 7) == 0 && e < 256) ? 1.0f : 0.0f;
            xgf[(rtg * 13 + 12) * 512 + e] = __float2bfloat16(val);
        }
        __syncthreads();
        // phase 2: xTf fragments from T
#pragma unroll
        for (int fh = 0; fh < 2; ++fh) {
            int f = fh * 32 + (tid & 31);
            int m8 = tid >> 5;                 // 0..7
            int m = n0 + m8 * 8;
            short8 o;
#pragma unroll
            for (int j = 0; j < 8; ++j) {
                __hip_bfloat16 h = T[f][m8 * 8 + j];
                o[j] = *reinterpret_cast<short*>(&h);
            }
            size_t addr = (((size_t)(b * 2 + fh) * 64 + (m >> 4)) * 2 + ((m >> 3) & 1)) * 256 + (f & 31) * 8;
            *(short8*)(xTf + addr) = o;
        }
    } else {
        int d = blockIdx.x - 128;
        const float* Wd = W + (size_t)d * 192 * 64;
        for (int i = tid; i < 1664; i += 256) {   // oh x ks x hi x l31
            int l31 = i & 31, hi2 = (i >> 5) & 1;
            int ks = (i >> 6) % 13, oh = (i >> 6) / 13;
            int o = oh * 32 + l31;
            short8 v;
#pragma unroll
            for (int j = 0; j < 8; ++j) {
                int k = ks * 16 + hi2 * 8 + j;
                float f = (k < 192) ? Wd[(size_t)k * 64 + o]
                                    : ((k == 192) ? bp[d * 64 + o] : 0.0f);
                v[j] = bf16bits(f);
            }
            size_t addr = ((((size_t)d * 2 + oh) * 13 + ks) * 2 + hi2) * 256 + l31 * 8;
            *(short8*)(wtf + addr) = v;
        }
    }
}

// ---------------------------------------------------------------------------
// K3/K4: MFMA spmm on fragment layouts — every operand load is wave-contiguous
// (base + lane*16B). 4 waves: (fh, kh); kh-split-K reduced via LDS.
// ---------------------------------------------------------------------------
#define LOADG(slot, g) do {                                                   \
    as[slot][0] = *(const short8*)(pa + ((g) * 4 + 0) * 512);                 \
    as[slot][1] = *(const short8*)(pa + ((g) * 4 + 1) * 512);                 \
    as[slot][2] = *(const short8*)(pa + ((g) * 4 + 2) * 512);                 \
    as[slot][3] = *(const short8*)(pa + ((g) * 4 + 3) * 512);                 \
    bs[slot][0] = *(const short8*)(pb + ((g) * 4 + 0) * 512);                 \
    bs[slot][1] = *(const short8*)(pb + ((g) * 4 + 1) * 512);                 \
    bs[slot][2] = *(const short8*)(pb + ((g) * 4 + 2) * 512);                 \
    bs[slot][3] = *(const short8*)(pb + ((g) * 4 + 3) * 512);                 \
} while (0)

template<bool FIRST>
__global__ __launch_bounds__(256) void k_spmm_mfma(const __hip_bfloat16* __restrict__ A16f,
                                                   const __hip_bfloat16* __restrict__ srcTf,
                                                   const float* __restrict__ xres,
                                                   __hip_bfloat16* __restrict__ xgf,
                                                   __hip_bfloat16* __restrict__ y1Tf) {
    __shared__ float P[2][32][67];
    int b = blockIdx.x >> 5;
    int ntile = blockIdx.x & 31;
    int n0 = ntile << 5;
    int tid = threadIdx.x;
    int wv = tid >> 6, lane = tid & 63;
    int fh = wv & 1, kh = wv >> 1;
    int l31 = lane & 31, hi = lane >> 5;

    const __hip_bfloat16* pa = srcTf + (((size_t)(b * 2 + fh) * 64 + kh * 32) * 2 + hi) * 256 + l31 * 8;
    const __hip_bfloat16* pb = A16f + (((size_t)(b * 32 + ntile) * 64 + kh * 32) * 2 + hi) * 256 + l31 * 8;

    f32x16 acc0, acc1;
#pragma unroll
    for (int i = 0; i < 16; ++i) { acc0[i] = 0.f; acc1[i] = 0.f; }

    short8 as[3][4], bs[3][4];
    LOADG(0, 0);
    LOADG(1, 1);
#pragma unroll
    for (int g = 0; g < 8; ++g) {
        if (g + 2 < 8) { LOADG((g + 2) % 3, g + 2); }
        int cu = g % 3;
        acc0 = __builtin_amdgcn_mfma_f32_32x32x16_bf16(as[cu][0], bs[cu][0], acc0, 0, 0, 0);
        acc1 = __builtin_amdgcn_mfma_f32_32x32x16_bf16(as[cu][1], bs[cu][1], acc1, 0, 0, 0);
        acc0 = __builtin_amdgcn_mfma_f32_32x32x16_bf16(as[cu][2], bs[cu][2], acc0, 0, 0, 0);
        acc1 = __builtin_amdgcn_mfma_f32_32x32x16_bf16(as[cu][3], bs[cu][3], acc1, 0, 0, 0);
    }
#pragma unroll
    for (int i = 0; i < 16; ++i) acc0[i] += acc1[i];

    if (kh == 1) {
#pragma unroll
        for (int r = 0; r < 16; ++r) {
            int f = hi * 4 + (r >> 2) * 8 + (r & 3);
            P[fh][l31][f] = acc0[r];
        }
    }
    __syncthreads();
    if (kh == 0) {
#pragma unroll
        for (int r = 0; r < 16; ++r) {
            int f = hi * 4 + (r >> 2) * 8 + (r & 3);
            acc0[r] += P[fh][l31][f];
        }

        int node = n0 + l31;
        size_t row = (size_t)(b << 10) + node;
        size_t rtg = (size_t)b * 32 + ntile;
#pragma unroll
        for (int rg = 0; rg < 4; ++rg) {
            int fb = fh * 32 + hi * 4 + rg * 8;
            float vx = acc0[rg * 4], vy = acc0[rg * 4 + 1];
            float vz = acc0[rg * 4 + 2], vw = acc0[rg * 4 + 3];
            if (!FIRST) {
                float4 xv = *(const float4*)(xres + row * 64 + fb);
                vx = 2.f * vx - xv.x; vy = 2.f * vy - xv.y;
                vz = 2.f * vz - xv.z; vw = 2.f * vw - xv.w;
            }
            bf4 o;
            o.a = __float2bfloat16(vx); o.b = __float2bfloat16(vy);
            o.c = __float2bfloat16(vz); o.d = __float2bfloat16(vw);
            int kstep = (FIRST ? 4 : 8) + fh * 2 + (rg >> 1);
            int hi2 = rg & 1;
            *(bf4*)(xgf + (rtg * 13 + kstep) * 512 + hi2 * 256 + l31 * 8 + hi * 4) = o;
        }
        if (FIRST) {
#pragma unroll
            for (int r = 0; r < 16; ++r) {
                int f = fh * 32 + hi * 4 + (r >> 2) * 8 + (r & 3);
                size_t addr = (((size_t)(b * 2 + fh) * 64 + ((n0 + l31) >> 4)) * 2 + ((l31 >> 3) & 1)) * 256
                              + (f & 31) * 8 + (l31 & 7);
                __hip_bfloat16 h = __float2bfloat16(acc0[r]);
                y1Tf[addr] = h;
            }
        }
    }
}

// ---------------------------------------------------------------------------
// K5: out[row,o] = sum_d e[row,d] * ( sum_k Wt[d][o][k] * xg[row][k] )
// 8 waves per 32-row tile; wave w owns d pair; all loads wave-contiguous.
// ---------------------------------------------------------------------------
__global__ __launch_bounds__(512) void k_fuse(const __hip_bfloat16* __restrict__ xgf,
                                              const __hip_bfloat16* __restrict__ wtf,
                                              const float* __restrict__ ne,
                                              const float* __restrict__ nt,
                                              float* __restrict__ out) {
    __shared__ float P[8][32][67];
    int rt = blockIdx.x;
    int m0 = rt * 32;
    int tid = threadIdx.x;
    int w = tid >> 6;
    int lane = tid & 63;
    int l31 = lane & 31, hi = lane >> 5;
    int b = m0 >> 10;
    int n = (m0 & 1023) + l31;

    int d0 = 2 * w, d1 = 2 * w + 1;
    float e0 = (d0 < 10) ? ne[n * 10 + d0] : nt[b * 6 + (d0 - 10)];
    float e1 = (d1 < 10) ? ne[n * 10 + d1] : nt[b * 6 + (d1 - 10)];

    short8 xf[13];
    const __hip_bfloat16* px = xgf + (size_t)rt * 6656 + hi * 256 + l31 * 8;
#pragma unroll
    for (int k = 0; k < 13; ++k) xf[k] = *(const short8*)(px + k * 512);

    f32x16 z00, z01, z10, z11;
#pragma unroll
    for (int i = 0; i < 16; ++i) { z00[i] = 0.f; z01[i] = 0.f; z10[i] = 0.f; z11[i] = 0.f; }

    const __hip_bfloat16* pw0 = wtf + (size_t)d0 * 13312 + hi * 256 + l31 * 8;
#pragma unroll
    for (int k = 0; k < 13; ++k) {
        short8 a00 = *(const short8*)(pw0 + k * 512);
        short8 a01 = *(const short8*)(pw0 + 6656 + k * 512);
        short8 a10 = *(const short8*)(pw0 + 13312 + k * 512);
        short8 a11 = *(const short8*)(pw0 + 13312 + 6656 + k * 512);
        z00 = __builtin_amdgcn_mfma_f32_32x32x16_bf16(a00, xf[k], z00, 0, 0, 0);
        z01 = __builtin_amdgcn_mfma_f32_32x32x16_bf16(a01, xf[k], z01, 0, 0, 0);
        z10 = __builtin_amdgcn_mfma_f32_32x32x16_bf16(a10, xf[k], z10, 0, 0, 0);
        z11 = __builtin_amdgcn_mfma_f32_32x32x16_bf16(a11, xf[k], z11, 0, 0, 0);
    }

#pragma unroll
    for (int r = 0; r < 16; ++r) {
        int o = (r & 3) + 8 * (r >> 2) + 4 * hi;
        P[w][l31][o]      = e0 * z00[r] + e1 * z10[r];
        P[w][l31][o + 32] = e0 * z01[r] + e1 * z11[r];
    }
    __syncthreads();

    int m = tid >> 4, o0 = (tid & 15) * 4;
    float s0 = 0.f, s1 = 0.f, s2 = 0.f, s3 = 0.f;
#pragma unroll
    for (int ww = 0; ww < 8; ++ww) {
        s0 += P[ww][m][o0];
        s1 += P[ww][m][o0 + 1];
        s2 += P[ww][m][o0 + 2];
        s3 += P[ww][m][o0 + 3];
    }
    *(float4*)(out + (size_t)(m0 + m) * 64 + o0) = make_float4(s0, s1, s2, s3);
}

// ---------------------------------------------------------------------------
extern "C" void kernel_launch(void* const* d_in, const int* in_sizes, int n_in,
                              void* d_out, int out_size, void* d_ws, size_t ws_size,
                              hipStream_t stream) {
    const float* x  = (const float*)d_in[0];   // [8,1024,64]
    const float* ne = (const float*)d_in[1];   // [1024,10]
    const float* t  = (const float*)d_in[2];   // [8,6]
    const float* nt = (const float*)d_in[3];   // [8,6]
    const float* W  = (const float*)d_in[5];   // [16,3,64,64]
    const float* bp = (const float*)d_in[6];   // [16,64]
    float* out = (float*)d_out;                // [8,1024,64]

    __hip_bfloat16* wsb = (__hip_bfloat16*)d_ws;
    __hip_bfloat16* A16f = wsb;                      // 8,388,608 elems
    __hip_bfloat16* xTf  = wsb + 8388608;            //   524,288
    __hip_bfloat16* y1Tf = wsb + 8912896;            //   524,288
    __hip_bfloat16* xgf  = wsb + 9437184;            // 256*13*512 = 1,703,936
    __hip_bfloat16* wtf  = wsb + 11141120;           // 16*2*13*512 = 212,992

    k_attn<<<BS * 32, 512, 0, stream>>>(ne, t, nt, A16f);
    k_prepw<<<144, 256, 0, stream>>>(x, W, bp, xTf, xgf, wtf);
    k_spmm_mfma<true ><<<BS * 32, 256, 0, stream>>>(A16f, xTf,  x, xgf, y1Tf);
    k_spmm_mfma<false><<<BS * 32, 256, 0, stream>>>(A16f, y1Tf, x, xgf, nullptr);
    k_fuse<<<BS * (NODE / 32), 512, 0, stream>>>(xgf, wtf, ne, nt, out);
}